// Round 14
// baseline (203.020 us; speedup 1.0000x reference)
//
#include <hip/hip_runtime.h>
#include <stdint.h>

#define BATCH 128
#define NTOK 4096
#define DD 64
#define NS 11
#define H3 192
#define MH 128
#define NCH 16

typedef __attribute__((ext_vector_type(8))) short bf16x8;
typedef __attribute__((ext_vector_type(4))) float f32x4;

static __device__ __forceinline__ float bf2f(unsigned short u){
  union { unsigned int i; float f; } v; v.i = ((unsigned int)u) << 16; return v.f;
}
static __device__ __forceinline__ unsigned short f2bf(float f){
  union { float f; unsigned int i; } v; v.f = f;
  unsigned int r = v.i + 0x7fffu + ((v.i >> 16) & 1u);
  return (unsigned short)(r >> 16);
}
static __device__ __forceinline__ unsigned int pack2(float a, float b){
  return (unsigned int)f2bf(a) | ((unsigned int)f2bf(b) << 16);
}
static __device__ __forceinline__ float lo16(unsigned int u){ union{unsigned int i;float f;}v; v.i = u << 16; return v.f; }
static __device__ __forceinline__ float hi16(unsigned int u){ union{unsigned int i;float f;}v; v.i = u & 0xffff0000u; return v.f; }

// ---------------------------------------------------------------------------
// prep_w: fold LN gamma into [Wk|Wv] (bf16, packed per-lane for MFMA B-frags),
// and beta into a fp32 bias row.  (unchanged)
// ---------------------------------------------------------------------------
__global__ __launch_bounds__(256) void prep_w(
    const float* __restrict__ gin, const float* __restrict__ bin,
    const float* __restrict__ Wk, const float* __restrict__ Wv,
    unsigned short* __restrict__ wpack, float* __restrict__ wbias)
{
  __shared__ float W2[64][128];
  int t = threadIdx.x;
  for (int i = t; i < 64*128; i += 256){
    int d = i >> 7, j = i & 127;
    W2[d][j] = (j < 64) ? Wk[d*64 + j] : Wv[d*64 + (j-64)];
  }
  __syncthreads();
  for (int j = t; j < 128; j += 256){
    float s = 0.f;
    for (int d = 0; d < 64; d++) s += bin[d] * W2[d][j];
    wbias[j] = s;
  }
  for (int i = t; i < 8192; i += 256){
    int e = i & 7;
    int l = (i >> 3) & 63;
    int ctks = i >> 9;
    int ks = ctks >> 3, ct = ctks & 7;
    int k = ks*32 + ((l >> 4) * 8) + e;
    int j = (l & 15)*8 + ct;
    wpack[i] = f2bf(gin[k] * W2[k][j]);
  }
}

// ---------------------------------------------------------------------------
// prep2: pack update-phase weights into bf16 MFMA B-fragment arrays. (unchanged)
// ---------------------------------------------------------------------------
__global__ __launch_bounds__(256) void prep2(
    const float* __restrict__ K, const float* __restrict__ R,
    const float* __restrict__ W1, const float* __restrict__ W2,
    const float* __restrict__ Wq,
    unsigned short* __restrict__ Kp, unsigned short* __restrict__ Rp,
    unsigned short* __restrict__ W1p, unsigned short* __restrict__ W2p,
    unsigned short* __restrict__ Wqp)
{
  int t = threadIdx.x;
  for (int i = t; i < 24*512; i += 256){
    int unit = i >> 9, r = i & 511, l = r >> 3, e = r & 7;
    int nt = unit >> 1, ks = unit & 1;
    int k = ks*32 + ((l >> 4) << 3) + e;
    int j = nt*16 + (l & 15);
    Kp[i] = f2bf(K[k*H3 + j]);
    Rp[i] = f2bf(R[k*H3 + j]);
  }
  for (int i = t; i < 16*512; i += 256){
    int unit = i >> 9, r = i & 511, l = r >> 3, e = r & 7;
    int nt = unit >> 1, ks = unit & 1;
    int k = ks*32 + ((l >> 4) << 3) + e;
    W1p[i] = f2bf(W1[k*MH + nt*16 + (l & 15)]);
  }
  for (int i = t; i < 16*512; i += 256){
    int unit = i >> 9, r = i & 511, l = r >> 3, e = r & 7;
    int nt = unit >> 2, ks = unit & 3;
    int k = ks*32 + ((l >> 4) << 3) + e;
    W2p[i] = f2bf(W2[k*64 + nt*16 + (l & 15)]);
  }
  for (int i = t; i < 8*512; i += 256){
    int unit = i >> 9, r = i & 511, l = r >> 3, e = r & 7;
    int nt = unit >> 1, ks = unit & 1;
    int k = ks*32 + ((l >> 4) << 3) + e;
    Wqp[i] = f2bf(Wq[k*64 + nt*16 + (l & 15)]);
  }
}

// ---------------------------------------------------------------------------
// proj_mfma: zero-LDS LN+GEMM + LDS-transposed vT epilogue.  (unchanged R12)
// ---------------------------------------------------------------------------
__global__ __launch_bounds__(256) void proj_mfma(
    const float* __restrict__ in,
    const unsigned short* __restrict__ wpack, const float* __restrict__ wbias,
    unsigned short* __restrict__ kout, unsigned short* __restrict__ vout)
{
  __shared__ unsigned short vsm[4][64][64];
  int t = threadIdx.x;
  int w = t >> 6, l = t & 63;
  int g = l >> 4, ln16 = l & 15;

  float4 bq0 = *(const float4*)(wbias + ln16*8);
  float4 bq1 = *(const float4*)(wbias + ln16*8 + 4);
  int coloff = (ln16 & 7) * 8;

  long tilebase = (long)blockIdx.x*256 + w*64;

  #pragma unroll
  for (int rt = 0; rt < 4; rt++){
    const float* rp = in + (tilebase + rt*16 + ln16)*64;
    float4 x0 = *(const float4*)(rp + g*8);
    float4 x1 = *(const float4*)(rp + g*8 + 4);
    float4 x2 = *(const float4*)(rp + 32 + g*8);
    float4 x3 = *(const float4*)(rp + 32 + g*8 + 4);
    float s  = ((x0.x+x0.y)+(x0.z+x0.w)) + ((x1.x+x1.y)+(x1.z+x1.w))
             + ((x2.x+x2.y)+(x2.z+x2.w)) + ((x3.x+x3.y)+(x3.z+x3.w));
    float s2 = (x0.x*x0.x+x0.y*x0.y+x0.z*x0.z+x0.w*x0.w)
             + (x1.x*x1.x+x1.y*x1.y+x1.z*x1.z+x1.w*x1.w)
             + (x2.x*x2.x+x2.y*x2.y+x2.z*x2.z+x2.w*x2.w)
             + (x3.x*x3.x+x3.y*x3.y+x3.z*x3.z+x3.w*x3.w);
    s  += __shfl_xor(s, 16);   s2 += __shfl_xor(s2, 16);
    s  += __shfl_xor(s, 32);   s2 += __shfl_xor(s2, 32);
    float m  = s * (1.0f/64.0f);
    float rs = rsqrtf(s2 * (1.0f/64.0f) - m*m + 1e-3f);
    union { uint4 u; bf16x8 v; } pa, pb;
    pa.u.x = pack2((x0.x-m)*rs, (x0.y-m)*rs);
    pa.u.y = pack2((x0.z-m)*rs, (x0.w-m)*rs);
    pa.u.z = pack2((x1.x-m)*rs, (x1.y-m)*rs);
    pa.u.w = pack2((x1.z-m)*rs, (x1.w-m)*rs);
    pb.u.x = pack2((x2.x-m)*rs, (x2.y-m)*rs);
    pb.u.y = pack2((x2.z-m)*rs, (x2.w-m)*rs);
    pb.u.z = pack2((x3.x-m)*rs, (x3.y-m)*rs);
    pb.u.w = pack2((x3.z-m)*rs, (x3.w-m)*rs);
    f32x4 acc[8];
    acc[0][0]=bq0.x; acc[0][1]=bq0.x; acc[0][2]=bq0.x; acc[0][3]=bq0.x;
    acc[1][0]=bq0.y; acc[1][1]=bq0.y; acc[1][2]=bq0.y; acc[1][3]=bq0.y;
    acc[2][0]=bq0.z; acc[2][1]=bq0.z; acc[2][2]=bq0.z; acc[2][3]=bq0.z;
    acc[3][0]=bq0.w; acc[3][1]=bq0.w; acc[3][2]=bq0.w; acc[3][3]=bq0.w;
    acc[4][0]=bq1.x; acc[4][1]=bq1.x; acc[4][2]=bq1.x; acc[4][3]=bq1.x;
    acc[5][0]=bq1.y; acc[5][1]=bq1.y; acc[5][2]=bq1.y; acc[5][3]=bq1.y;
    acc[6][0]=bq1.z; acc[6][1]=bq1.z; acc[6][2]=bq1.z; acc[6][3]=bq1.z;
    acc[7][0]=bq1.w; acc[7][1]=bq1.w; acc[7][2]=bq1.w; acc[7][3]=bq1.w;
    #pragma unroll
    for (int ct = 0; ct < 8; ct++){
      bf16x8 b0 = *(const bf16x8*)(wpack + ((0*8 + ct)*64 + l)*8);
      bf16x8 b1 = *(const bf16x8*)(wpack + ((1*8 + ct)*64 + l)*8);
      acc[ct] = __builtin_amdgcn_mfma_f32_16x16x32_bf16(pa.v, b0, acc[ct], 0, 0, 0);
      acc[ct] = __builtin_amdgcn_mfma_f32_16x16x32_bf16(pb.v, b1, acc[ct], 0, 0, 0);
    }
    long ob = tilebase + rt*16 + g*4;
    if (ln16 < 8){
      #pragma unroll
      for (int e = 0; e < 4; e++){
        uint4 p;
        p.x = pack2(acc[0][e], acc[1][e]);
        p.y = pack2(acc[2][e], acc[3][e]);
        p.z = pack2(acc[4][e], acc[5][e]);
        p.w = pack2(acc[6][e], acc[7][e]);
        *(uint4*)(kout + (ob + e)*64 + coloff) = p;
      }
    } else {
      int tok0 = rt*16 + g*4;
      int swz = (ln16 & 7) << 3;
      unsigned short* vs = &vsm[w][0][0];
      #pragma unroll
      for (int ct = 0; ct < 8; ct++){
        int d = coloff + ct;
        uint2 p2;
        p2.x = pack2(acc[ct][0], acc[ct][1]);
        p2.y = pack2(acc[ct][2], acc[ct][3]);
        *(uint2*)(vs + d*64 + (tok0 ^ swz)) = p2;
      }
    }
  }
  {
    long bb  = tilebase >> 12;
    int  nnb = (int)(tilebase & 4095);
    int dd = l >> 3, tk = l & 7;
    #pragma unroll
    for (int p = 0; p < 8; p++){
      int d = p*8 + dd;
      int tokl = (tk*8) ^ (p << 3);
      uint4 val = *(const uint4*)(&vsm[w][d][tokl]);
      *(uint4*)(vout + ((long)(bb*64 + d))*4096 + nnb + tk*8) = val;
    }
  }
}

// ---------------------------------------------------------------------------
// Init: slots0 = mu + exp(log_sigma)*noise; q1 = LN(slots0)@Wq * scale
// ---------------------------------------------------------------------------
__global__ __launch_bounds__(256) void init_kernel(
    const float* __restrict__ noise, const float* __restrict__ mu, const float* __restrict__ ls,
    const float* __restrict__ g_slots, const float* __restrict__ b_slots, const float* __restrict__ Wq,
    float* __restrict__ slots_out, float* __restrict__ q_out)
{
  __shared__ float s0[NS][64], lnb[NS][64];
  __shared__ float stm[NS], str[NS];
  int b = blockIdx.x, t = threadIdx.x;
  for (int i=t;i<NS*64;i+=256){
    int d = i & 63;
    float v0 = mu[d] + __expf(ls[d]) * noise[b*NS*64 + i];
    s0[i>>6][d] = v0;
    slots_out[b*NS*64 + i] = v0;
  }
  __syncthreads();
  if (t < NS){
    float ssum=0.f, ssq=0.f;
    for (int d=0;d<64;d++){ float x0=s0[t][d]; ssum+=x0; ssq+=x0*x0; }
    float mm = ssum*(1.f/64.f);
    stm[t]=mm; str[t]=rsqrtf(ssq*(1.f/64.f) - mm*mm + 1e-3f);
  }
  __syncthreads();
  for (int i=t;i<NS*64;i+=256){ int s=i>>6,d=i&63; lnb[s][d] = (s0[s][d]-stm[s])*str[s]*g_slots[d] + b_slots[d]; }
  __syncthreads();
  for (int i=t;i<NS*64;i+=256){
    int s=i>>6, j=i&63;
    float a1=0.f;
    for (int d=0;d<64;d++) a1 += lnb[s][d]*Wq[d*64+j];
    q_out[b*NS*64+i] = a1*0.125f;
  }
}

// ---------------------------------------------------------------------------
// Attention pass (R14): NCH=16 -> 2048 blocks for latency hiding.
// Per block: 256 rows; wave w owns 64 rows (4 grps).  MFMA QK^T + MFMA PV
// (K=64, 2 k-slices).  attnT[w][16 slots][64 tokens] per-wave, no barrier.
// ---------------------------------------------------------------------------
__global__ __launch_bounds__(256) void attn_kernel(
    const unsigned short* __restrict__ kk, const unsigned short* __restrict__ vT,
    const float* __restrict__ q, float* __restrict__ pnum, float* __restrict__ pcol)
{
  __shared__ float qsp[16][64];
  __shared__ unsigned short attnT[4][16][64];    // 8 KB
  __shared__ float numl[4][NS][64];
  __shared__ float csl[4][16];
  int b = blockIdx.x >> 4;
  int c = blockIdx.x & 15;
  int w = threadIdx.x >> 6;
  int l = threadIdx.x & 63;
  int t = threadIdx.x;
  for (int i = t; i < 16*64; i += 256){
    int s = i >> 6, d = i & 63;
    qsp[s][d] = (s < NS) ? q[b*(NS*64) + i] : 0.f;
  }
  __syncthreads();
  int ln16 = l & 15, g = l >> 4;
  bf16x8 aq0, aq1;
  #pragma unroll
  for (int e = 0; e < 8; e++){
    aq0[e] = (short)f2bf(qsp[ln16][g*8 + e]);
    aq1[e] = (short)f2bf(qsp[ln16][32 + g*8 + e]);
  }
  bool v0 = (g*4+0) < NS, v1 = (g*4+1) < NS, v2 = (g*4+2) < NS, v3 = (g*4+3) < NS;
  float csp0=0.f, csp1=0.f, csp2=0.f, csp3=0.f;
  long rowbase = (long)b*NTOK + c*256 + w*64;

  bf16x8 kb0[4], kb1[4];
  #pragma unroll
  for (int grp = 0; grp < 4; grp++){
    const unsigned short* kp = kk + (rowbase + grp*16 + ln16)*64 + g*8;
    kb0[grp] = *(const bf16x8*)(kp);
    kb1[grp] = *(const bf16x8*)(kp + 32);
  }
  #pragma unroll
  for (int grp = 0; grp < 4; grp++){
    f32x4 acc = {0.f,0.f,0.f,0.f};
    acc = __builtin_amdgcn_mfma_f32_16x16x32_bf16(aq0, kb0[grp], acc, 0, 0, 0);
    acc = __builtin_amdgcn_mfma_f32_16x16x32_bf16(aq1, kb1[grp], acc, 0, 0, 0);
    float mx = fmaxf(fmaxf(v0?acc[0]:-1e30f, v1?acc[1]:-1e30f),
                     fmaxf(v2?acc[2]:-1e30f, v3?acc[3]:-1e30f));
    mx = fmaxf(mx, __shfl_xor(mx, 16));
    mx = fmaxf(mx, __shfl_xor(mx, 32));
    float e0 = v0 ? __expf(acc[0]-mx) : 0.f;
    float e1 = v1 ? __expf(acc[1]-mx) : 0.f;
    float e2 = v2 ? __expf(acc[2]-mx) : 0.f;
    float e3 = v3 ? __expf(acc[3]-mx) : 0.f;
    float ssum = (e0+e1)+(e2+e3);
    ssum += __shfl_xor(ssum, 16);
    ssum += __shfl_xor(ssum, 32);
    float inv = 1.f/ssum;
    float a0 = v0 ? e0*inv + 1e-8f : 0.f;
    float a1 = v1 ? e1*inv + 1e-8f : 0.f;
    float a2 = v2 ? e2*inv + 1e-8f : 0.f;
    float a3 = v3 ? e3*inv + 1e-8f : 0.f;
    csp0 += a0; csp1 += a1; csp2 += a2; csp3 += a3;
    int row = grp*16 + ln16;
    attnT[w][g*4+0][row] = f2bf(a0);
    attnT[w][g*4+1][row] = f2bf(a1);
    attnT[w][g*4+2][row] = f2bf(a2);
    attnT[w][g*4+3][row] = f2bf(a3);
  }
  #pragma unroll
  for (int off = 1; off <= 8; off <<= 1){
    csp0 += __shfl_xor(csp0, off);
    csp1 += __shfl_xor(csp1, off);
    csp2 += __shfl_xor(csp2, off);
    csp3 += __shfl_xor(csp3, off);
  }
  if (ln16 == 0){
    csl[w][g*4+0] = csp0;
    csl[w][g*4+1] = csp1;
    csl[w][g*4+2] = csp2;
    csl[w][g*4+3] = csp3;
  }

  // ---- Phase B: PV via MFMA over this wave's 64 tokens (K=64) ----
  const unsigned short* vtb = vT + ((long)b*64 + ln16)*NTOK + (c*256 + w*64) + g*8;
  bf16x8 vf0[2], vf1[2], vf2[2], vf3[2];
  #pragma unroll
  for (int ks = 0; ks < 2; ks++){
    vf0[ks] = *(const bf16x8*)(vtb + 0*16*NTOK + ks*32);
    vf1[ks] = *(const bf16x8*)(vtb + 1*16*NTOK + ks*32);
    vf2[ks] = *(const bf16x8*)(vtb + 2*16*NTOK + ks*32);
    vf3[ks] = *(const bf16x8*)(vtb + 3*16*NTOK + ks*32);
  }
  f32x4 pacc0 = {0.f,0.f,0.f,0.f}, pacc1 = {0.f,0.f,0.f,0.f};
  f32x4 pacc2 = {0.f,0.f,0.f,0.f}, pacc3 = {0.f,0.f,0.f,0.f};
  #pragma unroll
  for (int ks = 0; ks < 2; ks++){
    bf16x8 af = *(const bf16x8*)&attnT[w][ln16][ks*32 + g*8];
    pacc0 = __builtin_amdgcn_mfma_f32_16x16x32_bf16(af, vf0[ks], pacc0, 0, 0, 0);
    pacc1 = __builtin_amdgcn_mfma_f32_16x16x32_bf16(af, vf1[ks], pacc1, 0, 0, 0);
    pacc2 = __builtin_amdgcn_mfma_f32_16x16x32_bf16(af, vf2[ks], pacc2, 0, 0, 0);
    pacc3 = __builtin_amdgcn_mfma_f32_16x16x32_bf16(af, vf3[ks], pacc3, 0, 0, 0);
  }
  #pragma unroll
  for (int e = 0; e < 4; e++){
    int s2 = g*4 + e;
    if (s2 < NS){
      numl[w][s2][0*16 + ln16] = pacc0[e];
      numl[w][s2][1*16 + ln16] = pacc1[e];
      numl[w][s2][2*16 + ln16] = pacc2[e];
      numl[w][s2][3*16 + ln16] = pacc3[e];
    }
  }
  __syncthreads();
  int pbase = (b*NCH + c)*NS;
  for (int i = t; i < NS*64; i += 256){
    int s2 = i >> 6, d = i & 63;
    pnum[(pbase + s2)*64 + d] = numl[0][s2][d] + numl[1][s2][d] + numl[2][s2][d] + numl[3][s2][d];
  }
  if (t < NS){
    pcol[pbase + t] = csl[0][t] + csl[1][t] + csl[2][t] + csl[3][t];
  }
}

// ---------------------------------------------------------------------------
// update_mfma (unchanged R13; NCH macro now 16 in the reduction loops).
// ---------------------------------------------------------------------------
__global__ __launch_bounds__(256) void update_mfma(
    const float* __restrict__ pnum, const float* __restrict__ pcol,
    const float* __restrict__ slots_in,
    const unsigned short* __restrict__ Kp, const unsigned short* __restrict__ Rp,
    const unsigned short* __restrict__ W1p, const unsigned short* __restrict__ W2p,
    const unsigned short* __restrict__ Wqp,
    const float* __restrict__ gbias, const float* __restrict__ b1,
    const float* __restrict__ b2,
    const float* __restrict__ g_slots, const float* __restrict__ b_slots,
    const float* __restrict__ g_mlp, const float* __restrict__ b_mlp,
    float* __restrict__ slots_out, float* __restrict__ q_out,
    float* __restrict__ final_out, int last)
{
  __shared__ unsigned short updb[16][64], spb[16][64], lnbb[16][64], h1b[16][128], lnb2b[16][64];
  __shared__ float spf[NS][64], snf[16][64], outb[16][64];
  __shared__ float mxs[16][H3], mhs[16][H3];
  __shared__ float cs[NS], stm[NS], str[NS];
  int b = blockIdx.x, t = threadIdx.x;
  int w = t >> 6, l = t & 63, g = l >> 4, ln16 = l & 15;

  if (t < NS){
    float ssum = 0.f;
    for (int c2 = 0; c2 < NCH; c2++) ssum += pcol[(b*NCH + c2)*NS + t];
    cs[t] = ssum;
  }
  __syncthreads();
  for (int i = t; i < NS*64; i += 256){
    int s = i >> 6, d = i & 63;
    float acc = 0.f;
    for (int c2 = 0; c2 < NCH; c2++) acc += pnum[((b*NCH + c2)*NS + s)*64 + d];
    updb[s][d] = f2bf(acc / cs[s]);
    float sp = slots_in[b*NS*64 + i];
    spf[s][d] = sp;
    spb[s][d] = f2bf(sp);
  }
  __syncthreads();

  {
    const unsigned short* ab = (w < 2) ? &updb[0][0] : &spb[0][0];
    bf16x8 a0 = *(const bf16x8*)(ab + ln16*64 + g*8);
    bf16x8 a1 = *(const bf16x8*)(ab + ln16*64 + 32 + g*8);
    const unsigned short* bp = (w < 2) ? Kp : Rp;
    float* outs = (w < 2) ? &mxs[0][0] : &mhs[0][0];
    int boff = (w < 2) ? 0 : H3;
    int nt0 = (w & 1) * 6;
    #pragma unroll
    for (int u = 0; u < 6; u++){
      int nt = nt0 + u;
      bf16x8 bf0 = *(const bf16x8*)(bp + (nt*2 + 0)*512 + l*8);
      bf16x8 bf1 = *(const bf16x8*)(bp + (nt*2 + 1)*512 + l*8);
      f32x4 acc = {0.f,0.f,0.f,0.f};
      acc = __builtin_amdgcn_mfma_f32_16x16x32_bf16(a0, bf0, acc, 0, 0, 0);
      acc = __builtin_amdgcn_mfma_f32_16x16x32_bf16(a1, bf1, acc, 0, 0, 0);
      int j = nt*16 + ln16;
      float bb = gbias[boff + j];
      #pragma unroll
      for (int e = 0; e < 4; e++) outs[(g*4 + e)*H3 + j] = acc[e] + bb;
    }
  }
  __syncthreads();

  for (int i = t; i < NS*64; i += 256){
    int s = i >> 6, d = i & 63;
    float z = 1.f/(1.f + __expf(-(mxs[s][d] + mhs[s][d])));
    float r = 1.f/(1.f + __expf(-(mxs[s][64+d] + mhs[s][64+d])));
    float cand = tanhf(mxs[s][128+d] + r*mhs[s][128+d]);
    snf[s][d] = z*spf[s][d] + (1.f - z)*cand;
  }
  __syncthreads();
  if (t < NS){
    float ssum=0.f, ssq=0.f;
    for (int d=0; d<64; d++){ float x0 = snf[t][d]; ssum += x0; ssq += x0*x0; }
    float mm = ssum*(1.f/64.f);
    stm[t]=mm; str[t]=rsqrtf(ssq*(1.f/64.f) - mm*mm + 1e-3f);
  }
  __syncthreads();
  for (int i = t; i < NS*64; i += 256){
    int s = i >> 6, d = i & 63;
    lnbb[s][d] = f2bf((snf[s][d]-stm[s])*str[s]*g_mlp[d] + b_mlp[d]);
  }
  __syncthreads();

  {
    bf16x8 a0 = *(const bf16x8*)(&lnbb[0][0] + ln16*64 + g*8);
    bf16x8 a1 = *(const bf16x8*)(&lnbb[0][0] + ln16*64 + 32 + g*8);
    #pragma unroll
    for (int u = 0; u < 2; u++){
      int nt = w*2 + u;
      bf16x8 bf0 = *(const bf16x8*)(W1p + (nt*2 + 0)*512 + l*8);
      bf16x8 bf1 = *(const bf16x8*)(W1p + (nt*2 + 1)*512 + l*8);
      f32x4 acc = {0.f,0.f,0.f,0.f};
      acc = __builtin_amdgcn_mfma_f32_16x16x32_bf16(a0, bf0, acc, 0, 0, 0);
      acc = __builtin_amdgcn_mfma_f32_16x16x32_bf16(a1, bf1, acc, 0, 0, 0);
      int j = nt*16 + ln16;
      float bb = b1[j];
      #pragma unroll
      for (int e = 0; e < 4; e++) h1b[g*4 + e][j] = f2bf(fmaxf(acc[e] + bb, 0.f));
    }
  }
  __syncthreads();

  {
    f32x4 acc = {0.f,0.f,0.f,0.f};
    #pragma unroll
    for (int ks = 0; ks < 4; ks++){
      bf16x8 a = *(const bf16x8*)(&h1b[0][0] + ln16*128 + ks*32 + g*8);
      bf16x8 bf0 = *(const bf16x8*)(W2p + (w*4 + ks)*512 + l*8);
      acc = __builtin_amdgcn_mfma_f32_16x16x32_bf16(a, bf0, acc, 0, 0, 0);
    }
    int d = w*16 + ln16;
    float bb = b2[d];
    #pragma unroll
    for (int e = 0; e < 4; e++) outb[g*4 + e][d] = acc[e] + bb + snf[g*4 + e][d];
  }
  __syncthreads();

  for (int i = t; i < NS*64; i += 256){
    int s = i >> 6, d = i & 63;
    float v = outb[s][d];
    slots_out[b*NS*64 + i] = v;
    if (last) final_out[b*NS*64 + i] = v;
  }
  if (t < NS){
    float ssum=0.f, ssq=0.f;
    for (int d=0; d<64; d++){ float x0 = outb[t][d]; ssum += x0; ssq += x0*x0; }
    float mm = ssum*(1.f/64.f);
    stm[t]=mm; str[t]=rsqrtf(ssq*(1.f/64.f) - mm*mm + 1e-3f);
  }
  __syncthreads();
  if (last) return;
  for (int i = t; i < NS*64; i += 256){
    int s = i >> 6, d = i & 63;
    lnb2b[s][d] = f2bf((outb[s][d]-stm[s])*str[s]*g_slots[d] + b_slots[d]);
  }
  __syncthreads();

  {
    bf16x8 a0 = *(const bf16x8*)(&lnb2b[0][0] + ln16*64 + g*8);
    bf16x8 a1 = *(const bf16x8*)(&lnb2b[0][0] + ln16*64 + 32 + g*8);
    bf16x8 bf0 = *(const bf16x8*)(Wqp + (w*2 + 0)*512 + l*8);
    bf16x8 bf1 = *(const bf16x8*)(Wqp + (w*2 + 1)*512 + l*8);
    f32x4 acc = {0.f,0.f,0.f,0.f};
    acc = __builtin_amdgcn_mfma_f32_16x16x32_bf16(a0, bf0, acc, 0, 0, 0);
    acc = __builtin_amdgcn_mfma_f32_16x16x32_bf16(a1, bf1, acc, 0, 0, 0);
    int j = w*16 + ln16;
    #pragma unroll
    for (int e = 0; e < 4; e++){
      int s = g*4 + e;
      if (s < NS) q_out[b*NS*64 + s*64 + j] = acc[e]*0.125f;
    }
  }
}

extern "C" void kernel_launch(void* const* d_in, const int* in_sizes, int n_in,
                              void* d_out, int out_size, void* d_ws, size_t ws_size,
                              hipStream_t stream)
{
  const float* inputs = (const float*)d_in[0];
  const float* noise  = (const float*)d_in[1];
  const float* gin    = (const float*)d_in[2];
  const float* bin    = (const float*)d_in[3];
  const float* gsl    = (const float*)d_in[4];
  const float* bsl    = (const float*)d_in[5];
  const float* gml    = (const float*)d_in[6];
  const float* bml    = (const float*)d_in[7];
  const float* mu     = (const float*)d_in[8];
  const float* lsg    = (const float*)d_in[9];
  const float* Wq     = (const float*)d_in[10];
  const float* Wk     = (const float*)d_in[11];
  const float* Wv     = (const float*)d_in[12];
  const float* gk     = (const float*)d_in[13];
  const float* gr     = (const float*)d_in[14];
  const float* gb     = (const float*)d_in[15];
  const float* W1     = (const float*)d_in[16];
  const float* b1     = (const float*)d_in[17];
  const float* W2     = (const float*)d_in[18];
  const float* b2     = (const float*)d_in[19];

  char* ws = (char*)d_ws;
  unsigned short* kbuf = (unsigned short*)(ws);
  unsigned short* vbuf = (unsigned short*)(ws + 67108864);   // vT[b][64][NTOK]
  float* qbuf  = (float*)(ws + 134217728);
  float* slots = (float*)(ws + 134742016);
  float* pnum  = (float*)(ws + 135266304);                   // 128*16*11*64*4 = 5767168
  float* pcol  = (float*)(ws + 141033472);                   // 128*16*11*4 = 90112
  unsigned short* wpack = (unsigned short*)(ws + 141123584);
  float* wbias = (float*)(ws + 141139968);
  unsigned short* Kp  = (unsigned short*)(ws + 141140480);
  unsigned short* Rp  = (unsigned short*)(ws + 141165056);
  unsigned short* W1p = (unsigned short*)(ws + 141189632);
  unsigned short* W2p = (unsigned short*)(ws + 141206016);
  unsigned short* Wqp = (unsigned short*)(ws + 141222400);
  float* out   = (float*)d_out;

  hipLaunchKernelGGL(prep_w, dim3(1), dim3(256), 0, stream, gin, bin, Wk, Wv, wpack, wbias);
  hipLaunchKernelGGL(prep2, dim3(1), dim3(256), 0, stream, gk, gr, W1, W2, Wq, Kp, Rp, W1p, W2p, Wqp);
  hipLaunchKernelGGL(proj_mfma, dim3(2048), dim3(256), 0, stream, inputs, wpack, wbias, kbuf, vbuf);
  hipLaunchKernelGGL(init_kernel, dim3(128), dim3(256), 0, stream, noise, mu, lsg, gsl, bsl, Wq, slots, qbuf);
  for (int it = 0; it < 3; it++){
    hipLaunchKernelGGL(attn_kernel, dim3(2048), dim3(256), 0, stream, kbuf, vbuf, qbuf, pnum, pcol);
    hipLaunchKernelGGL(update_mfma, dim3(128), dim3(256), 0, stream,
        pnum, pcol, slots, Kp, Rp, W1p, W2p, Wqp, gb, b1, b2, gsl, bsl, gml, bml,
        slots, qbuf, out, (it==2) ? 1 : 0);
  }
}

// Round 15
// 170.846 us; speedup vs baseline: 1.1883x; 1.1883x over previous
//
#include <hip/hip_runtime.h>
#include <stdint.h>

#define BATCH 128
#define NTOK 4096
#define DD 64
#define NS 11
#define H3 192
#define MH 128
#define NCH 8

typedef __attribute__((ext_vector_type(8))) short bf16x8;
typedef __attribute__((ext_vector_type(4))) float f32x4;

static __device__ __forceinline__ float bf2f(unsigned short u){
  union { unsigned int i; float f; } v; v.i = ((unsigned int)u) << 16; return v.f;
}
static __device__ __forceinline__ unsigned short f2bf(float f){
  union { float f; unsigned int i; } v; v.f = f;
  unsigned int r = v.i + 0x7fffu + ((v.i >> 16) & 1u);
  return (unsigned short)(r >> 16);
}
static __device__ __forceinline__ unsigned int pack2(float a, float b){
  return (unsigned int)f2bf(a) | ((unsigned int)f2bf(b) << 16);
}
static __device__ __forceinline__ float lo16(unsigned int u){ union{unsigned int i;float f;}v; v.i = u << 16; return v.f; }
static __device__ __forceinline__ float hi16(unsigned int u){ union{unsigned int i;float f;}v; v.i = u & 0xffff0000u; return v.f; }

// ---------------------------------------------------------------------------
// prep_w (R15: 9 blocks).  Every block loads W2 to LDS; block 0 computes the
// folded bias; blocks 1..8 each pack 1024 wpack entries.
// ---------------------------------------------------------------------------
__global__ __launch_bounds__(256) void prep_w(
    const float* __restrict__ gin, const float* __restrict__ bin,
    const float* __restrict__ Wk, const float* __restrict__ Wv,
    unsigned short* __restrict__ wpack, float* __restrict__ wbias)
{
  __shared__ float W2[64][128];
  int t = threadIdx.x, bid = blockIdx.x;
  for (int i = t; i < 64*128; i += 256){
    int d = i >> 7, j = i & 127;
    W2[d][j] = (j < 64) ? Wk[d*64 + j] : Wv[d*64 + (j-64)];
  }
  __syncthreads();
  if (bid == 0){
    for (int j = t; j < 128; j += 256){
      float s = 0.f;
      for (int d = 0; d < 64; d++) s += bin[d] * W2[d][j];
      wbias[j] = s;
    }
  } else {
    int base = (bid - 1) * 1024;
    for (int o = t; o < 1024; o += 256){
      int i = base + o;
      int e = i & 7;
      int l = (i >> 3) & 63;
      int ctks = i >> 9;
      int ks = ctks >> 3, ct = ctks & 7;
      int k = ks*32 + ((l >> 4) * 8) + e;
      int j = (l & 15)*8 + ct;
      wpack[i] = f2bf(gin[k] * W2[k][j]);
    }
  }
}

// ---------------------------------------------------------------------------
// prep2 (R15: 32 blocks, grid-stride).  Packs update-phase weights into bf16
// MFMA B-fragment arrays.
// ---------------------------------------------------------------------------
__global__ __launch_bounds__(256) void prep2(
    const float* __restrict__ K, const float* __restrict__ R,
    const float* __restrict__ W1, const float* __restrict__ W2,
    const float* __restrict__ Wq,
    unsigned short* __restrict__ Kp, unsigned short* __restrict__ Rp,
    unsigned short* __restrict__ W1p, unsigned short* __restrict__ W2p,
    unsigned short* __restrict__ Wqp)
{
  int t0 = blockIdx.x*256 + threadIdx.x;
  int stride = gridDim.x*256;
  for (int i = t0; i < 24*512; i += stride){
    int unit = i >> 9, r = i & 511, l = r >> 3, e = r & 7;
    int nt = unit >> 1, ks = unit & 1;
    int k = ks*32 + ((l >> 4) << 3) + e;
    int j = nt*16 + (l & 15);
    Kp[i] = f2bf(K[k*H3 + j]);
    Rp[i] = f2bf(R[k*H3 + j]);
  }
  for (int i = t0; i < 16*512; i += stride){
    int unit = i >> 9, r = i & 511, l = r >> 3, e = r & 7;
    int nt = unit >> 1, ks = unit & 1;
    int k = ks*32 + ((l >> 4) << 3) + e;
    W1p[i] = f2bf(W1[k*MH + nt*16 + (l & 15)]);
  }
  for (int i = t0; i < 16*512; i += stride){
    int unit = i >> 9, r = i & 511, l = r >> 3, e = r & 7;
    int nt = unit >> 2, ks = unit & 3;
    int k = ks*32 + ((l >> 4) << 3) + e;
    W2p[i] = f2bf(W2[k*64 + nt*16 + (l & 15)]);
  }
  for (int i = t0; i < 8*512; i += stride){
    int unit = i >> 9, r = i & 511, l = r >> 3, e = r & 7;
    int nt = unit >> 1, ks = unit & 1;
    int k = ks*32 + ((l >> 4) << 3) + e;
    Wqp[i] = f2bf(Wq[k*64 + nt*16 + (l & 15)]);
  }
}

// ---------------------------------------------------------------------------
// proj_mfma: zero-LDS LN+GEMM + LDS-transposed vT epilogue.  (unchanged R12)
// ---------------------------------------------------------------------------
__global__ __launch_bounds__(256) void proj_mfma(
    const float* __restrict__ in,
    const unsigned short* __restrict__ wpack, const float* __restrict__ wbias,
    unsigned short* __restrict__ kout, unsigned short* __restrict__ vout)
{
  __shared__ unsigned short vsm[4][64][64];
  int t = threadIdx.x;
  int w = t >> 6, l = t & 63;
  int g = l >> 4, ln16 = l & 15;

  float4 bq0 = *(const float4*)(wbias + ln16*8);
  float4 bq1 = *(const float4*)(wbias + ln16*8 + 4);
  int coloff = (ln16 & 7) * 8;

  long tilebase = (long)blockIdx.x*256 + w*64;

  #pragma unroll
  for (int rt = 0; rt < 4; rt++){
    const float* rp = in + (tilebase + rt*16 + ln16)*64;
    float4 x0 = *(const float4*)(rp + g*8);
    float4 x1 = *(const float4*)(rp + g*8 + 4);
    float4 x2 = *(const float4*)(rp + 32 + g*8);
    float4 x3 = *(const float4*)(rp + 32 + g*8 + 4);
    float s  = ((x0.x+x0.y)+(x0.z+x0.w)) + ((x1.x+x1.y)+(x1.z+x1.w))
             + ((x2.x+x2.y)+(x2.z+x2.w)) + ((x3.x+x3.y)+(x3.z+x3.w));
    float s2 = (x0.x*x0.x+x0.y*x0.y+x0.z*x0.z+x0.w*x0.w)
             + (x1.x*x1.x+x1.y*x1.y+x1.z*x1.z+x1.w*x1.w)
             + (x2.x*x2.x+x2.y*x2.y+x2.z*x2.z+x2.w*x2.w)
             + (x3.x*x3.x+x3.y*x3.y+x3.z*x3.z+x3.w*x3.w);
    s  += __shfl_xor(s, 16);   s2 += __shfl_xor(s2, 16);
    s  += __shfl_xor(s, 32);   s2 += __shfl_xor(s2, 32);
    float m  = s * (1.0f/64.0f);
    float rs = rsqrtf(s2 * (1.0f/64.0f) - m*m + 1e-3f);
    union { uint4 u; bf16x8 v; } pa, pb;
    pa.u.x = pack2((x0.x-m)*rs, (x0.y-m)*rs);
    pa.u.y = pack2((x0.z-m)*rs, (x0.w-m)*rs);
    pa.u.z = pack2((x1.x-m)*rs, (x1.y-m)*rs);
    pa.u.w = pack2((x1.z-m)*rs, (x1.w-m)*rs);
    pb.u.x = pack2((x2.x-m)*rs, (x2.y-m)*rs);
    pb.u.y = pack2((x2.z-m)*rs, (x2.w-m)*rs);
    pb.u.z = pack2((x3.x-m)*rs, (x3.y-m)*rs);
    pb.u.w = pack2((x3.z-m)*rs, (x3.w-m)*rs);
    f32x4 acc[8];
    acc[0][0]=bq0.x; acc[0][1]=bq0.x; acc[0][2]=bq0.x; acc[0][3]=bq0.x;
    acc[1][0]=bq0.y; acc[1][1]=bq0.y; acc[1][2]=bq0.y; acc[1][3]=bq0.y;
    acc[2][0]=bq0.z; acc[2][1]=bq0.z; acc[2][2]=bq0.z; acc[2][3]=bq0.z;
    acc[3][0]=bq0.w; acc[3][1]=bq0.w; acc[3][2]=bq0.w; acc[3][3]=bq0.w;
    acc[4][0]=bq1.x; acc[4][1]=bq1.x; acc[4][2]=bq1.x; acc[4][3]=bq1.x;
    acc[5][0]=bq1.y; acc[5][1]=bq1.y; acc[5][2]=bq1.y; acc[5][3]=bq1.y;
    acc[6][0]=bq1.z; acc[6][1]=bq1.z; acc[6][2]=bq1.z; acc[6][3]=bq1.z;
    acc[7][0]=bq1.w; acc[7][1]=bq1.w; acc[7][2]=bq1.w; acc[7][3]=bq1.w;
    #pragma unroll
    for (int ct = 0; ct < 8; ct++){
      bf16x8 b0 = *(const bf16x8*)(wpack + ((0*8 + ct)*64 + l)*8);
      bf16x8 b1 = *(const bf16x8*)(wpack + ((1*8 + ct)*64 + l)*8);
      acc[ct] = __builtin_amdgcn_mfma_f32_16x16x32_bf16(pa.v, b0, acc[ct], 0, 0, 0);
      acc[ct] = __builtin_amdgcn_mfma_f32_16x16x32_bf16(pb.v, b1, acc[ct], 0, 0, 0);
    }
    long ob = tilebase + rt*16 + g*4;
    if (ln16 < 8){
      #pragma unroll
      for (int e = 0; e < 4; e++){
        uint4 p;
        p.x = pack2(acc[0][e], acc[1][e]);
        p.y = pack2(acc[2][e], acc[3][e]);
        p.z = pack2(acc[4][e], acc[5][e]);
        p.w = pack2(acc[6][e], acc[7][e]);
        *(uint4*)(kout + (ob + e)*64 + coloff) = p;
      }
    } else {
      int tok0 = rt*16 + g*4;
      int swz = (ln16 & 7) << 3;
      unsigned short* vs = &vsm[w][0][0];
      #pragma unroll
      for (int ct = 0; ct < 8; ct++){
        int d = coloff + ct;
        uint2 p2;
        p2.x = pack2(acc[ct][0], acc[ct][1]);
        p2.y = pack2(acc[ct][2], acc[ct][3]);
        *(uint2*)(vs + d*64 + (tok0 ^ swz)) = p2;
      }
    }
  }
  {
    long bb  = tilebase >> 12;
    int  nnb = (int)(tilebase & 4095);
    int dd = l >> 3, tk = l & 7;
    #pragma unroll
    for (int p = 0; p < 8; p++){
      int d = p*8 + dd;
      int tokl = (tk*8) ^ (p << 3);
      uint4 val = *(const uint4*)(&vsm[w][d][tokl]);
      *(uint4*)(vout + ((long)(bb*64 + d))*4096 + nnb + tk*8) = val;
    }
  }
}

// ---------------------------------------------------------------------------
// Init: slots0 = mu + exp(log_sigma)*noise; q1 = LN(slots0)@Wq * scale
// ---------------------------------------------------------------------------
__global__ __launch_bounds__(256) void init_kernel(
    const float* __restrict__ noise, const float* __restrict__ mu, const float* __restrict__ ls,
    const float* __restrict__ g_slots, const float* __restrict__ b_slots, const float* __restrict__ Wq,
    float* __restrict__ slots_out, float* __restrict__ q_out)
{
  __shared__ float s0[NS][64], lnb[NS][64];
  __shared__ float stm[NS], str[NS];
  int b = blockIdx.x, t = threadIdx.x;
  for (int i=t;i<NS*64;i+=256){
    int d = i & 63;
    float v0 = mu[d] + __expf(ls[d]) * noise[b*NS*64 + i];
    s0[i>>6][d] = v0;
    slots_out[b*NS*64 + i] = v0;
  }
  __syncthreads();
  if (t < NS){
    float ssum=0.f, ssq=0.f;
    for (int d=0;d<64;d++){ float x0=s0[t][d]; ssum+=x0; ssq+=x0*x0; }
    float mm = ssum*(1.f/64.f);
    stm[t]=mm; str[t]=rsqrtf(ssq*(1.f/64.f) - mm*mm + 1e-3f);
  }
  __syncthreads();
  for (int i=t;i<NS*64;i+=256){ int s=i>>6,d=i&63; lnb[s][d] = (s0[s][d]-stm[s])*str[s]*g_slots[d] + b_slots[d]; }
  __syncthreads();
  for (int i=t;i<NS*64;i+=256){
    int s=i>>6, j=i&63;
    float a1=0.f;
    for (int d=0;d<64;d++) a1 += lnb[s][d]*Wq[d*64+j];
    q_out[b*NS*64+i] = a1*0.125f;
  }
}

// ---------------------------------------------------------------------------
// Attention pass (R13 config: NCH=8, 1024 blocks): MFMA QK^T + MFMA PV.
// ---------------------------------------------------------------------------
__global__ __launch_bounds__(256) void attn_kernel(
    const unsigned short* __restrict__ kk, const unsigned short* __restrict__ vT,
    const float* __restrict__ q, float* __restrict__ pnum, float* __restrict__ pcol)
{
  __shared__ float qsp[16][64];
  __shared__ unsigned short attnT[4][16][128];
  __shared__ float numl[4][NS][64];
  __shared__ float csl[4][16];
  int b = blockIdx.x >> 3;
  int c = blockIdx.x & 7;
  int w = threadIdx.x >> 6;
  int l = threadIdx.x & 63;
  int t = threadIdx.x;
  for (int i = t; i < 16*64; i += 256){
    int s = i >> 6, d = i & 63;
    qsp[s][d] = (s < NS) ? q[b*(NS*64) + i] : 0.f;
  }
  __syncthreads();
  int ln16 = l & 15, g = l >> 4;
  bf16x8 aq0, aq1;
  #pragma unroll
  for (int e = 0; e < 8; e++){
    aq0[e] = (short)f2bf(qsp[ln16][g*8 + e]);
    aq1[e] = (short)f2bf(qsp[ln16][32 + g*8 + e]);
  }
  bool v0 = (g*4+0) < NS, v1 = (g*4+1) < NS, v2 = (g*4+2) < NS, v3 = (g*4+3) < NS;
  float csp0=0.f, csp1=0.f, csp2=0.f, csp3=0.f;
  long rowbase = (long)b*NTOK + c*512 + w*128;

  bf16x8 kb0[8], kb1[8];
  #pragma unroll
  for (int grp = 0; grp < 8; grp++){
    const unsigned short* kp = kk + (rowbase + grp*16 + ln16)*64 + g*8;
    kb0[grp] = *(const bf16x8*)(kp);
    kb1[grp] = *(const bf16x8*)(kp + 32);
  }
  #pragma unroll
  for (int grp = 0; grp < 8; grp++){
    f32x4 acc = {0.f,0.f,0.f,0.f};
    acc = __builtin_amdgcn_mfma_f32_16x16x32_bf16(aq0, kb0[grp], acc, 0, 0, 0);
    acc = __builtin_amdgcn_mfma_f32_16x16x32_bf16(aq1, kb1[grp], acc, 0, 0, 0);
    float mx = fmaxf(fmaxf(v0?acc[0]:-1e30f, v1?acc[1]:-1e30f),
                     fmaxf(v2?acc[2]:-1e30f, v3?acc[3]:-1e30f));
    mx = fmaxf(mx, __shfl_xor(mx, 16));
    mx = fmaxf(mx, __shfl_xor(mx, 32));
    float e0 = v0 ? __expf(acc[0]-mx) : 0.f;
    float e1 = v1 ? __expf(acc[1]-mx) : 0.f;
    float e2 = v2 ? __expf(acc[2]-mx) : 0.f;
    float e3 = v3 ? __expf(acc[3]-mx) : 0.f;
    float ssum = (e0+e1)+(e2+e3);
    ssum += __shfl_xor(ssum, 16);
    ssum += __shfl_xor(ssum, 32);
    float inv = 1.f/ssum;
    float a0 = v0 ? e0*inv + 1e-8f : 0.f;
    float a1 = v1 ? e1*inv + 1e-8f : 0.f;
    float a2 = v2 ? e2*inv + 1e-8f : 0.f;
    float a3 = v3 ? e3*inv + 1e-8f : 0.f;
    csp0 += a0; csp1 += a1; csp2 += a2; csp3 += a3;
    int row = grp*16 + ln16;
    attnT[w][g*4+0][row] = f2bf(a0);
    attnT[w][g*4+1][row] = f2bf(a1);
    attnT[w][g*4+2][row] = f2bf(a2);
    attnT[w][g*4+3][row] = f2bf(a3);
  }
  #pragma unroll
  for (int off = 1; off <= 8; off <<= 1){
    csp0 += __shfl_xor(csp0, off);
    csp1 += __shfl_xor(csp1, off);
    csp2 += __shfl_xor(csp2, off);
    csp3 += __shfl_xor(csp3, off);
  }
  if (ln16 == 0){
    csl[w][g*4+0] = csp0;
    csl[w][g*4+1] = csp1;
    csl[w][g*4+2] = csp2;
    csl[w][g*4+3] = csp3;
  }

  const unsigned short* vtb = vT + ((long)b*64 + ln16)*NTOK + (c*512 + w*128) + g*8;
  bf16x8 vf0[4], vf1[4], vf2[4], vf3[4];
  #pragma unroll
  for (int ks = 0; ks < 4; ks++){
    vf0[ks] = *(const bf16x8*)(vtb + 0*16*NTOK + ks*32);
    vf1[ks] = *(const bf16x8*)(vtb + 1*16*NTOK + ks*32);
    vf2[ks] = *(const bf16x8*)(vtb + 2*16*NTOK + ks*32);
    vf3[ks] = *(const bf16x8*)(vtb + 3*16*NTOK + ks*32);
  }
  f32x4 pacc0 = {0.f,0.f,0.f,0.f}, pacc1 = {0.f,0.f,0.f,0.f};
  f32x4 pacc2 = {0.f,0.f,0.f,0.f}, pacc3 = {0.f,0.f,0.f,0.f};
  #pragma unroll
  for (int ks = 0; ks < 4; ks++){
    bf16x8 af = *(const bf16x8*)&attnT[w][ln16][ks*32 + g*8];
    pacc0 = __builtin_amdgcn_mfma_f32_16x16x32_bf16(af, vf0[ks], pacc0, 0, 0, 0);
    pacc1 = __builtin_amdgcn_mfma_f32_16x16x32_bf16(af, vf1[ks], pacc1, 0, 0, 0);
    pacc2 = __builtin_amdgcn_mfma_f32_16x16x32_bf16(af, vf2[ks], pacc2, 0, 0, 0);
    pacc3 = __builtin_amdgcn_mfma_f32_16x16x32_bf16(af, vf3[ks], pacc3, 0, 0, 0);
  }
  #pragma unroll
  for (int e = 0; e < 4; e++){
    int s2 = g*4 + e;
    if (s2 < NS){
      numl[w][s2][0*16 + ln16] = pacc0[e];
      numl[w][s2][1*16 + ln16] = pacc1[e];
      numl[w][s2][2*16 + ln16] = pacc2[e];
      numl[w][s2][3*16 + ln16] = pacc3[e];
    }
  }
  __syncthreads();
  int pbase = (b*NCH + c)*NS;
  for (int i = t; i < NS*64; i += 256){
    int s2 = i >> 6, d = i & 63;
    pnum[(pbase + s2)*64 + d] = numl[0][s2][d] + numl[1][s2][d] + numl[2][s2][d] + numl[3][s2][d];
  }
  if (t < NS){
    pcol[pbase + t] = csl[0][t] + csl[1][t] + csl[2][t] + csl[3][t];
  }
}

// ---------------------------------------------------------------------------
// update_mfma (unchanged R13).
// ---------------------------------------------------------------------------
__global__ __launch_bounds__(256) void update_mfma(
    const float* __restrict__ pnum, const float* __restrict__ pcol,
    const float* __restrict__ slots_in,
    const unsigned short* __restrict__ Kp, const unsigned short* __restrict__ Rp,
    const unsigned short* __restrict__ W1p, const unsigned short* __restrict__ W2p,
    const unsigned short* __restrict__ Wqp,
    const float* __restrict__ gbias, const float* __restrict__ b1,
    const float* __restrict__ b2,
    const float* __restrict__ g_slots, const float* __restrict__ b_slots,
    const float* __restrict__ g_mlp, const float* __restrict__ b_mlp,
    float* __restrict__ slots_out, float* __restrict__ q_out,
    float* __restrict__ final_out, int last)
{
  __shared__ unsigned short updb[16][64], spb[16][64], lnbb[16][64], h1b[16][128], lnb2b[16][64];
  __shared__ float spf[NS][64], snf[16][64], outb[16][64];
  __shared__ float mxs[16][H3], mhs[16][H3];
  __shared__ float cs[NS], stm[NS], str[NS];
  int b = blockIdx.x, t = threadIdx.x;
  int w = t >> 6, l = t & 63, g = l >> 4, ln16 = l & 15;

  if (t < NS){
    float ssum = 0.f;
    for (int c2 = 0; c2 < NCH; c2++) ssum += pcol[(b*NCH + c2)*NS + t];
    cs[t] = ssum;
  }
  __syncthreads();
  for (int i = t; i < NS*64; i += 256){
    int s = i >> 6, d = i & 63;
    float acc = 0.f;
    for (int c2 = 0; c2 < NCH; c2++) acc += pnum[((b*NCH + c2)*NS + s)*64 + d];
    updb[s][d] = f2bf(acc / cs[s]);
    float sp = slots_in[b*NS*64 + i];
    spf[s][d] = sp;
    spb[s][d] = f2bf(sp);
  }
  __syncthreads();

  {
    const unsigned short* ab = (w < 2) ? &updb[0][0] : &spb[0][0];
    bf16x8 a0 = *(const bf16x8*)(ab + ln16*64 + g*8);
    bf16x8 a1 = *(const bf16x8*)(ab + ln16*64 + 32 + g*8);
    const unsigned short* bp = (w < 2) ? Kp : Rp;
    float* outs = (w < 2) ? &mxs[0][0] : &mhs[0][0];
    int boff = (w < 2) ? 0 : H3;
    int nt0 = (w & 1) * 6;
    #pragma unroll
    for (int u = 0; u < 6; u++){
      int nt = nt0 + u;
      bf16x8 bf0 = *(const bf16x8*)(bp + (nt*2 + 0)*512 + l*8);
      bf16x8 bf1 = *(const bf16x8*)(bp + (nt*2 + 1)*512 + l*8);
      f32x4 acc = {0.f,0.f,0.f,0.f};
      acc = __builtin_amdgcn_mfma_f32_16x16x32_bf16(a0, bf0, acc, 0, 0, 0);
      acc = __builtin_amdgcn_mfma_f32_16x16x32_bf16(a1, bf1, acc, 0, 0, 0);
      int j = nt*16 + ln16;
      float bb = gbias[boff + j];
      #pragma unroll
      for (int e = 0; e < 4; e++) outs[(g*4 + e)*H3 + j] = acc[e] + bb;
    }
  }
  __syncthreads();

  for (int i = t; i < NS*64; i += 256){
    int s = i >> 6, d = i & 63;
    float z = 1.f/(1.f + __expf(-(mxs[s][d] + mhs[s][d])));
    float r = 1.f/(1.f + __expf(-(mxs[s][64+d] + mhs[s][64+d])));
    float cand = tanhf(mxs[s][128+d] + r*mhs[s][128+d]);
    snf[s][d] = z*spf[s][d] + (1.f - z)*cand;
  }
  __syncthreads();
  if (t < NS){
    float ssum=0.f, ssq=0.f;
    for (int d=0; d<64; d++){ float x0 = snf[t][d]; ssum += x0; ssq += x0*x0; }
    float mm = ssum*(1.f/64.f);
    stm[t]=mm; str[t]=rsqrtf(ssq*(1.f/64.f) - mm*mm + 1e-3f);
  }
  __syncthreads();
  for (int i = t; i < NS*64; i += 256){
    int s = i >> 6, d = i & 63;
    lnbb[s][d] = f2bf((snf[s][d]-stm[s])*str[s]*g_mlp[d] + b_mlp[d]);
  }
  __syncthreads();

  {
    bf16x8 a0 = *(const bf16x8*)(&lnbb[0][0] + ln16*64 + g*8);
    bf16x8 a1 = *(const bf16x8*)(&lnbb[0][0] + ln16*64 + 32 + g*8);
    #pragma unroll
    for (int u = 0; u < 2; u++){
      int nt = w*2 + u;
      bf16x8 bf0 = *(const bf16x8*)(W1p + (nt*2 + 0)*512 + l*8);
      bf16x8 bf1 = *(const bf16x8*)(W1p + (nt*2 + 1)*512 + l*8);
      f32x4 acc = {0.f,0.f,0.f,0.f};
      acc = __builtin_amdgcn_mfma_f32_16x16x32_bf16(a0, bf0, acc, 0, 0, 0);
      acc = __builtin_amdgcn_mfma_f32_16x16x32_bf16(a1, bf1, acc, 0, 0, 0);
      int j = nt*16 + ln16;
      float bb = b1[j];
      #pragma unroll
      for (int e = 0; e < 4; e++) h1b[g*4 + e][j] = f2bf(fmaxf(acc[e] + bb, 0.f));
    }
  }
  __syncthreads();

  {
    f32x4 acc = {0.f,0.f,0.f,0.f};
    #pragma unroll
    for (int ks = 0; ks < 4; ks++){
      bf16x8 a = *(const bf16x8*)(&h1b[0][0] + ln16*128 + ks*32 + g*8);
      bf16x8 bf0 = *(const bf16x8*)(W2p + (w*4 + ks)*512 + l*8);
      acc = __builtin_amdgcn_mfma_f32_16x16x32_bf16(a, bf0, acc, 0, 0, 0);
    }
    int d = w*16 + ln16;
    float bb = b2[d];
    #pragma unroll
    for (int e = 0; e < 4; e++) outb[g*4 + e][d] = acc[e] + bb + snf[g*4 + e][d];
  }
  __syncthreads();

  for (int i = t; i < NS*64; i += 256){
    int s = i >> 6, d = i & 63;
    float v = outb[s][d];
    slots_out[b*NS*64 + i] = v;
    if (last) final_out[b*NS*64 + i] = v;
  }
  if (t < NS){
    float ssum=0.f, ssq=0.f;
    for (int d=0; d<64; d++){ float x0 = outb[t][d]; ssum += x0; ssq += x0*x0; }
    float mm = ssum*(1.f/64.f);
    stm[t]=mm; str[t]=rsqrtf(ssq*(1.f/64.f) - mm*mm + 1e-3f);
  }
  __syncthreads();
  if (last) return;
  for (int i = t; i < NS*64; i += 256){
    int s = i >> 6, d = i & 63;
    lnb2b[s][d] = f2bf((outb[s][d]-stm[s])*str[s]*g_slots[d] + b_slots[d]);
  }
  __syncthreads();

  {
    bf16x8 a0 = *(const bf16x8*)(&lnb2b[0][0] + ln16*64 + g*8);
    bf16x8 a1 = *(const bf16x8*)(&lnb2b[0][0] + ln16*64 + 32 + g*8);
    bf16x8 bf0 = *(const bf16x8*)(Wqp + (w*2 + 0)*512 + l*8);
    bf16x8 bf1 = *(const bf16x8*)(Wqp + (w*2 + 1)*512 + l*8);
    f32x4 acc = {0.f,0.f,0.f,0.f};
    acc = __builtin_amdgcn_mfma_f32_16x16x32_bf16(a0, bf0, acc, 0, 0, 0);
    acc = __builtin_amdgcn_mfma_f32_16x16x32_bf16(a1, bf1, acc, 0, 0, 0);
    int j = w*16 + ln16;
    #pragma unroll
    for (int e = 0; e < 4; e++){
      int s = g*4 + e;
      if (s < NS) q_out[b*NS*64 + s*64 + j] = acc[e]*0.125f;
    }
  }
}

extern "C" void kernel_launch(void* const* d_in, const int* in_sizes, int n_in,
                              void* d_out, int out_size, void* d_ws, size_t ws_size,
                              hipStream_t stream)
{
  const float* inputs = (const float*)d_in[0];
  const float* noise  = (const float*)d_in[1];
  const float* gin    = (const float*)d_in[2];
  const float* bin    = (const float*)d_in[3];
  const float* gsl    = (const float*)d_in[4];
  const float* bsl    = (const float*)d_in[5];
  const float* gml    = (const float*)d_in[6];
  const float* bml    = (const float*)d_in[7];
  const float* mu     = (const float*)d_in[8];
  const float* lsg    = (const float*)d_in[9];
  const float* Wq     = (const float*)d_in[10];
  const float* Wk     = (const float*)d_in[11];
  const float* Wv     = (const float*)d_in[12];
  const float* gk     = (const float*)d_in[13];
  const float* gr     = (const float*)d_in[14];
  const float* gb     = (const float*)d_in[15];
  const float* W1     = (const float*)d_in[16];
  const float* b1     = (const float*)d_in[17];
  const float* W2     = (const float*)d_in[18];
  const float* b2     = (const float*)d_in[19];

  char* ws = (char*)d_ws;
  unsigned short* kbuf = (unsigned short*)(ws);
  unsigned short* vbuf = (unsigned short*)(ws + 67108864);   // vT[b][64][NTOK]
  float* qbuf  = (float*)(ws + 134217728);
  float* slots = (float*)(ws + 134217728 + 524288);
  float* pnum  = (float*)(ws + 134217728 + 1048576);
  float* pcol  = (float*)(ws + 134217728 + 1048576 + 2883584);
  unsigned short* wpack = (unsigned short*)(ws + 138194944);
  float* wbias = (float*)(ws + 138211328);
  unsigned short* Kp  = (unsigned short*)(ws + 138211840);
  unsigned short* Rp  = (unsigned short*)(ws + 138211840 + 24576);
  unsigned short* W1p = (unsigned short*)(ws + 138211840 + 49152);
  unsigned short* W2p = (unsigned short*)(ws + 138211840 + 65536);
  unsigned short* Wqp = (unsigned short*)(ws + 138211840 + 81920);
  float* out   = (float*)d_out;

  hipLaunchKernelGGL(prep_w, dim3(9), dim3(256), 0, stream, gin, bin, Wk, Wv, wpack, wbias);
  hipLaunchKernelGGL(prep2, dim3(32), dim3(256), 0, stream, gk, gr, W1, W2, Wq, Kp, Rp, W1p, W2p, Wqp);
  hipLaunchKernelGGL(proj_mfma, dim3(2048), dim3(256), 0, stream, inputs, wpack, wbias, kbuf, vbuf);
  hipLaunchKernelGGL(init_kernel, dim3(128), dim3(256), 0, stream, noise, mu, lsg, gsl, bsl, Wq, slots, qbuf);
  for (int it = 0; it < 3; it++){
    hipLaunchKernelGGL(attn_kernel, dim3(1024), dim3(256), 0, stream, kbuf, vbuf, qbuf, pnum, pcol);
    hipLaunchKernelGGL(update_mfma, dim3(128), dim3(256), 0, stream,
        pnum, pcol, slots, Kp, Rp, W1p, W2p, Wqp, gb, b1, b2, gsl, bsl, gml, bml,
        slots, qbuf, out, (it==2) ? 1 : 0);
  }
}